// Round 1
// baseline (454.836 us; speedup 1.0000x reference)
//
#include <hip/hip_runtime.h>

// Causal single-head attention, B=4 S=4096 Dm=256 Dqk=64, fp32 in/out.
// Strategy: bf16-MFMA projections into workspace (v stored transposed
// [B,256,S]), then flash-attention (online softmax) with
// mfma_f32_16x16x32_bf16 for QK^T and PV. fp32 accumulation throughout.
// Workspace use: qb 2MB + kb 2MB + vtb 8MB = 12MB.

#define BATCH 4
#define SEQ   4096
#define DMODEL 256
#define DQK   64

typedef __bf16 bf16x8 __attribute__((ext_vector_type(8)));
typedef float  f32x4  __attribute__((ext_vector_type(4)));

__device__ __forceinline__ unsigned short f2bf(float f) {
    unsigned int u = __builtin_bit_cast(unsigned int, f);
    u += 0x7fffu + ((u >> 16) & 1u);   // RNE round to bf16
    return (unsigned short)(u >> 16);
}

__device__ __forceinline__ bf16x8 ld_bf16x8(const unsigned short* p) {
    uint4 u = *(const uint4*)p;        // 16B -> ds_read_b128 / dwordx4
    return __builtin_bit_cast(bf16x8, u);
}

// ---------------------------------------------------------------------------
// Projection: out[b,s,e] = sum_d X[b,s,d] * W[e,d], e in [0,64). out bf16.
// One block = 64 s-rows. 256 threads, 4 waves x 16 rows.
// ---------------------------------------------------------------------------
__global__ __launch_bounds__(256) void proj_qk_kernel(const float* __restrict__ X,
                                                      const float* __restrict__ W,
                                                      unsigned short* __restrict__ out) {
    __shared__ unsigned short Xs[64][256];   // s-rows x d
    __shared__ unsigned short Ws[64][256];   // e-rows x d
    const int s0 = blockIdx.x * 64;
    const int b  = blockIdx.y;
    const int tid  = threadIdx.x;
    const int wave = tid >> 6, lane = tid & 63;
    const int quad = lane >> 4, ln = lane & 15;

    // stage X tile (64x256 fp32 -> bf16) and W (64x256)
    #pragma unroll
    for (int i = 0; i < 16; ++i) {
        int f = i * 256 + tid;
        int row = f >> 6, c4 = f & 63;
        float4 xv = *(const float4*)&X[(size_t)(b * SEQ + s0 + row) * DMODEL + c4 * 4];
        ushort4 h; h.x = f2bf(xv.x); h.y = f2bf(xv.y); h.z = f2bf(xv.z); h.w = f2bf(xv.w);
        *(ushort4*)&Xs[row][c4 * 4] = h;
        float4 wv = *(const float4*)&W[(size_t)row * DMODEL + c4 * 4];
        ushort4 g; g.x = f2bf(wv.x); g.y = f2bf(wv.y); g.z = f2bf(wv.z); g.w = f2bf(wv.w);
        *(ushort4*)&Ws[row][c4 * 4] = g;
    }
    __syncthreads();

    f32x4 acc[4] = {};
    #pragma unroll
    for (int ks = 0; ks < 8; ++ks) {
        bf16x8 a = ld_bf16x8(&Xs[16 * wave + ln][ks * 32 + quad * 8]);
        #pragma unroll
        for (int ct = 0; ct < 4; ++ct) {
            bf16x8 bb = ld_bf16x8(&Ws[ct * 16 + ln][ks * 32 + quad * 8]);
            acc[ct] = __builtin_amdgcn_mfma_f32_16x16x32_bf16(a, bb, acc[ct], 0, 0, 0);
        }
    }
    #pragma unroll
    for (int ct = 0; ct < 4; ++ct)
        #pragma unroll
        for (int j = 0; j < 4; ++j) {
            int row = 16 * wave + quad * 4 + j;     // C-layout: row = quad*4+reg
            int col = ct * 16 + ln;                 //           col = lane&15
            out[(size_t)(b * SEQ + s0 + row) * DQK + col] = f2bf(acc[ct][j]);
        }
}

// ---------------------------------------------------------------------------
// V projection, transposed output: out[b,e,s] = sum_d X[b,s,d] * W[e,d].
// Computed as D[e][s] = Wv (A) x enc_v^T (B) so frags AND stores are contiguous.
// One block = 64 s-cols, loops over 4 chunks of 64 e-rows.
// ---------------------------------------------------------------------------
__global__ __launch_bounds__(256) void proj_vt_kernel(const float* __restrict__ X,
                                                      const float* __restrict__ W,
                                                      unsigned short* __restrict__ out) {
    __shared__ unsigned short Xs[64][256];   // s-rows x d (B operand)
    __shared__ unsigned short Ws[64][256];   // e-rows x d (A operand)
    const int s0 = blockIdx.x * 64;
    const int b  = blockIdx.y;
    const int tid  = threadIdx.x;
    const int wave = tid >> 6, lane = tid & 63;
    const int quad = lane >> 4, ln = lane & 15;

    #pragma unroll
    for (int i = 0; i < 16; ++i) {
        int f = i * 256 + tid;
        int row = f >> 6, c4 = f & 63;
        float4 xv = *(const float4*)&X[(size_t)(b * SEQ + s0 + row) * DMODEL + c4 * 4];
        ushort4 h; h.x = f2bf(xv.x); h.y = f2bf(xv.y); h.z = f2bf(xv.z); h.w = f2bf(xv.w);
        *(ushort4*)&Xs[row][c4 * 4] = h;
    }

    for (int ec = 0; ec < 4; ++ec) {
        __syncthreads();   // prev chunk's frag reads done (also covers Xs staging)
        #pragma unroll
        for (int i = 0; i < 16; ++i) {
            int f = i * 256 + tid;
            int row = f >> 6, c4 = f & 63;
            float4 wv = *(const float4*)&W[(size_t)(ec * 64 + row) * DMODEL + c4 * 4];
            ushort4 g; g.x = f2bf(wv.x); g.y = f2bf(wv.y); g.z = f2bf(wv.z); g.w = f2bf(wv.w);
            *(ushort4*)&Ws[row][c4 * 4] = g;
        }
        __syncthreads();

        f32x4 acc[4] = {};
        #pragma unroll
        for (int ks = 0; ks < 8; ++ks) {
            bf16x8 a = ld_bf16x8(&Ws[16 * wave + ln][ks * 32 + quad * 8]);  // A: e-rows
            #pragma unroll
            for (int ct = 0; ct < 4; ++ct) {
                bf16x8 bb = ld_bf16x8(&Xs[ct * 16 + ln][ks * 32 + quad * 8]); // B: s-rows
                acc[ct] = __builtin_amdgcn_mfma_f32_16x16x32_bf16(a, bb, acc[ct], 0, 0, 0);
            }
        }
        #pragma unroll
        for (int ct = 0; ct < 4; ++ct)
            #pragma unroll
            for (int j = 0; j < 4; ++j) {
                int e    = ec * 64 + 16 * wave + quad * 4 + j;
                int scol = s0 + ct * 16 + ln;
                out[(size_t)(b * DMODEL + e) * SEQ + scol] = f2bf(acc[ct][j]);
            }
    }
}

// ---------------------------------------------------------------------------
// Flash attention, causal. Block = (q-tile t of 64 rows, batch b).
// 4 waves x 16 Q-rows each. K-tiles of 64. Online softmax; O fp32 in regs.
// ---------------------------------------------------------------------------
__global__ __launch_bounds__(256) void attn_kernel(const unsigned short* __restrict__ qb,
                                                   const unsigned short* __restrict__ kb,
                                                   const unsigned short* __restrict__ vtb,
                                                   float* __restrict__ out) {
    __shared__ unsigned short Ks[64][72];    // k-rows(n) x dqk, pad->144B rows
    __shared__ unsigned short Vs[256][72];   // feature(n) x seq-k (V^T)
    __shared__ unsigned short Ps[64][72];    // probs, bf16, row-major

    const int t  = blockIdx.x;
    const int b  = blockIdx.y;
    const int r0 = t * 64;
    const int tid  = threadIdx.x;
    const int wave = tid >> 6, lane = tid & 63;
    const int quad = lane >> 4, ln = lane & 15;

    // Q A-fragments held in regs for the whole block
    const unsigned short* qrow = &qb[(size_t)(b * SEQ + r0 + 16 * wave + ln) * DQK];
    const bf16x8 qf0 = ld_bf16x8(qrow + quad * 8);
    const bf16x8 qf1 = ld_bf16x8(qrow + 32 + quad * 8);

    f32x4 o[16] = {};
    float mrun[4] = {-3e38f, -3e38f, -3e38f, -3e38f};
    float lrun[4] = {0.f, 0.f, 0.f, 0.f};
    const float cfac = 0.18033688011112042f;   // log2(e) / sqrt(64)

    for (int jt = 0; jt <= t; ++jt) {
        const int j0 = jt * 64;
        __syncthreads();   // prior iter's Vs/Ps reads complete before restaging
        #pragma unroll
        for (int i = 0; i < 2; ++i) {          // K tile: 64x64 bf16
            int c = tid + i * 256;
            int row = c >> 3, ch = c & 7;
            *(uint4*)&Ks[row][ch * 8] =
                *(const uint4*)&kb[(size_t)(b * SEQ + j0 + row) * DQK + ch * 8];
        }
        #pragma unroll
        for (int i = 0; i < 8; ++i) {          // V^T tile: 256x64 bf16
            int c = tid + i * 256;
            int row = c >> 3, ch = c & 7;
            *(uint4*)&Vs[row][ch * 8] =
                *(const uint4*)&vtb[(size_t)(b * DMODEL + row) * SEQ + j0 + ch * 8];
        }
        __syncthreads();

        // S = Q K^T : 4 col-tiles of 16
        f32x4 sa[4];
        #pragma unroll
        for (int ct = 0; ct < 4; ++ct) {
            bf16x8 b0 = ld_bf16x8(&Ks[ct * 16 + ln][quad * 8]);
            bf16x8 b1 = ld_bf16x8(&Ks[ct * 16 + ln][32 + quad * 8]);
            f32x4 acc = {};
            acc = __builtin_amdgcn_mfma_f32_16x16x32_bf16(qf0, b0, acc, 0, 0, 0);
            acc = __builtin_amdgcn_mfma_f32_16x16x32_bf16(qf1, b1, acc, 0, 0, 0);
            sa[ct] = acc;
        }

        // scale + causal mask (only the diagonal tile needs masking)
        float sc[4][4];
        #pragma unroll
        for (int ct = 0; ct < 4; ++ct)
            #pragma unroll
            for (int j = 0; j < 4; ++j) {
                float v = sa[ct][j] * cfac;
                if (jt == t) {
                    int row_l = 16 * wave + quad * 4 + j;
                    int col_l = ct * 16 + ln;
                    if (col_l > row_l) v = -3e38f;
                }
                sc[ct][j] = v;
            }

        // online softmax. Row (quad*4+j) lives in this quad's 16 lanes.
        float tm[4];
        #pragma unroll
        for (int j = 0; j < 4; ++j) {
            tm[j] = fmaxf(fmaxf(sc[0][j], sc[1][j]), fmaxf(sc[2][j], sc[3][j]));
        }
        #pragma unroll
        for (int off = 1; off < 16; off <<= 1)
            #pragma unroll
            for (int j = 0; j < 4; ++j)
                tm[j] = fmaxf(tm[j], __shfl_xor(tm[j], off));

        float alpha[4];
        #pragma unroll
        for (int j = 0; j < 4; ++j) {
            float nm = fmaxf(mrun[j], tm[j]);
            alpha[j] = __builtin_exp2f(mrun[j] - nm);   // both -3e38 -> 0 -> 1, safe
            mrun[j] = nm;
        }

        float p[4][4], rs[4];
        #pragma unroll
        for (int ct = 0; ct < 4; ++ct)
            #pragma unroll
            for (int j = 0; j < 4; ++j)
                p[ct][j] = __builtin_exp2f(sc[ct][j] - mrun[j]);   // masked -> exp2(-huge)=0
        #pragma unroll
        for (int j = 0; j < 4; ++j)
            rs[j] = (p[0][j] + p[1][j]) + (p[2][j] + p[3][j]);
        #pragma unroll
        for (int off = 1; off < 16; off <<= 1)
            #pragma unroll
            for (int j = 0; j < 4; ++j)
                rs[j] += __shfl_xor(rs[j], off);
        #pragma unroll
        for (int j = 0; j < 4; ++j)
            lrun[j] = alpha[j] * lrun[j] + rs[j];

        // rescale O by alpha (row mapping identical to C layout)
        #pragma unroll
        for (int et = 0; et < 16; ++et)
            #pragma unroll
            for (int j = 0; j < 4; ++j)
                o[et][j] *= alpha[j];

        // P -> LDS (bf16) for PV A-operand
        #pragma unroll
        for (int ct = 0; ct < 4; ++ct)
            #pragma unroll
            for (int j = 0; j < 4; ++j)
                Ps[16 * wave + quad * 4 + j][ct * 16 + ln] = f2bf(p[ct][j]);
        __syncthreads();

        // O += P V : A from Ps (own wave's 16 rows), B from Vs (feature rows)
        bf16x8 a0 = ld_bf16x8(&Ps[16 * wave + ln][quad * 8]);
        bf16x8 a1 = ld_bf16x8(&Ps[16 * wave + ln][32 + quad * 8]);
        #pragma unroll
        for (int et = 0; et < 16; ++et) {
            bf16x8 b0 = ld_bf16x8(&Vs[et * 16 + ln][quad * 8]);
            bf16x8 b1 = ld_bf16x8(&Vs[et * 16 + ln][32 + quad * 8]);
            o[et] = __builtin_amdgcn_mfma_f32_16x16x32_bf16(a0, b0, o[et], 0, 0, 0);
            o[et] = __builtin_amdgcn_mfma_f32_16x16x32_bf16(a1, b1, o[et], 0, 0, 0);
        }
    }

    // epilogue: normalize and store fp32
    float inv[4];
    #pragma unroll
    for (int j = 0; j < 4; ++j) inv[j] = 1.0f / lrun[j];
    #pragma unroll
    for (int et = 0; et < 16; ++et)
        #pragma unroll
        for (int j = 0; j < 4; ++j) {
            int row = r0 + 16 * wave + quad * 4 + j;
            int col = et * 16 + ln;
            out[(size_t)(b * SEQ + row) * DMODEL + col] = o[et][j] * inv[j];
        }
}

// ---------------------------------------------------------------------------
extern "C" void kernel_launch(void* const* d_in, const int* in_sizes, int n_in,
                              void* d_out, int out_size, void* d_ws, size_t ws_size,
                              hipStream_t stream) {
    const float* enc_q = (const float*)d_in[0];
    const float* enc_k = (const float*)d_in[1];
    const float* enc_v = (const float*)d_in[2];
    // d_in[3] = mask: deterministic causal triu — not needed.
    const float* Wq = (const float*)d_in[4];
    const float* Wk = (const float*)d_in[5];
    const float* Wv = (const float*)d_in[6];
    float* out = (float*)d_out;

    unsigned short* qb  = (unsigned short*)d_ws;                 // [B,S,64]  2MB
    unsigned short* kbp = qb  + (size_t)BATCH * SEQ * DQK;       // [B,S,64]  2MB
    unsigned short* vtb = kbp + (size_t)BATCH * SEQ * DQK;       // [B,256,S] 8MB

    dim3 grid(SEQ / 64, BATCH);
    proj_qk_kernel<<<grid, 256, 0, stream>>>(enc_q, Wq, qb);
    proj_qk_kernel<<<grid, 256, 0, stream>>>(enc_k, Wk, kbp);
    proj_vt_kernel<<<grid, 256, 0, stream>>>(enc_v, Wv, vtb);
    attn_kernel<<<grid, 256, 0, stream>>>(qb, kbp, vtb, out);
}

// Round 2
// 268.344 us; speedup vs baseline: 1.6950x; 1.6950x over previous
//
#include <hip/hip_runtime.h>

// Causal single-head attention, B=4 S=4096 Dm=256 Dqk=64, fp32 in/out.
// R2: frag-packed operand buffers (projections emit MFMA-fragment layout via
// shfl_xor(32) repack), 32x32x16 MFMAs, S computed transposed so P lands
// k-contiguous per lane, no-max softmax (den accumulated per-lane), LDS only
// for the P round-trip (double-buffered, 1 barrier/iter). Q-tile 32, K-tile
// 128, 512 blocks folded big+small for balance, 2 blocks/CU.
// ws: qf 2MB + kf 2MB + vf 8MB = 12MB (frag-packed bf16).

#define BATCH 4
#define SEQ   4096
#define DM    256
#define DQK   64

typedef __bf16 bf16x8 __attribute__((ext_vector_type(8)));
typedef float  f32x16 __attribute__((ext_vector_type(16)));

__device__ __forceinline__ unsigned int rnd16(unsigned int u) {
    return u + 0x7fffu + ((u >> 16) & 1u);          // RNE to bf16 in high half
}
__device__ __forceinline__ unsigned int pk2bf(float lo, float hi) {
    unsigned int a = rnd16(__builtin_bit_cast(unsigned int, lo));
    unsigned int b = rnd16(__builtin_bit_cast(unsigned int, hi));
    return (a >> 16) | (b & 0xffff0000u);           // elem0 low, elem1 high
}
__device__ __forceinline__ bf16x8 u4bf(uint4 u) { return __builtin_bit_cast(bf16x8, u); }

// load+convert 8 consecutive fp32 -> bf16x8
__device__ __forceinline__ bf16x8 cvt8(const float* p) {
    float4 a = *(const float4*)p;
    float4 b = *(const float4*)(p + 4);
    uint4 r;
    r.x = pk2bf(a.x, a.y); r.y = pk2bf(a.z, a.w);
    r.z = pk2bf(b.x, b.y); r.w = pk2bf(b.z, b.w);
    return u4bf(r);
}

// Repack a 32x32x16 MFMA accumulator (C-layout: col=lane&31, row=(r&3)+8(r>>2)+4(lane>>5))
// into two 1KB fragment chunks (frag: lane = 32*(k>>3 &1) + col, k-contiguous bytes)
// and store. kc chunk kcg_base+kc holds k-local = kc*16 + (lane>>5)*8 + i.
__device__ __forceinline__ void repack_store(const f32x16& acc, int q2, int l,
                                             uint4* __restrict__ out, size_t tile_ofs_u4) {
    unsigned int d0[4], d1[4], p0[4], p1[4];
#pragma unroll
    for (int h = 0; h < 4; ++h) {
        d0[h] = pk2bf(acc[4*h + 0], acc[4*h + 1]);
        d1[h] = pk2bf(acc[4*h + 2], acc[4*h + 3]);
        p0[h] = __shfl_xor((int)d0[h], 32);
        p1[h] = __shfl_xor((int)d1[h], 32);
    }
#pragma unroll
    for (int kc = 0; kc < 2; ++kc) {
        int h = 2*kc + q2;
        uint4 v = (q2 == 0) ? make_uint4(d0[h], d1[h], p0[h], p1[h])
                            : make_uint4(p0[h], p1[h], d0[h], d1[h]);
        out[tile_ofs_u4 + (size_t)kc * 64 + l] = v;
    }
}

// ---------------------------------------------------------------------------
// Q/K projection, transposed: D[d_qk][s] = sum_d W[d_qk][d] * X[s][d].
// A = W rows (m=d_qk), B = X rows (n=s). Output frag-packed: B/A-frag chunks
// (1KB per (s-tile32, d-chunk16)). grid (S/64, B, 2={q,k}), 256 thr.
// ---------------------------------------------------------------------------
__global__ __launch_bounds__(256) void proj_qk(const float* __restrict__ Xq, const float* __restrict__ Xk,
                                               const float* __restrict__ Wq, const float* __restrict__ Wk,
                                               uint4* __restrict__ qf, uint4* __restrict__ kf) {
    const int z = blockIdx.z;
    const float* X = z ? Xk : Xq;
    const float* W = z ? Wk : Wq;
    uint4* OUT = z ? kf : qf;
    const int bx = blockIdx.x, b = blockIdx.y;
    const int tid = threadIdx.x, w = tid >> 6, l = tid & 63, ln = l & 31, q2 = l >> 5;
    const int mt = w >> 1, nt = w & 1;                 // d_qk-half, s-subtile
    const float* arow = &W[(size_t)(mt*32 + ln) * DM + q2*8];
    const float* brow = &X[((size_t)b*SEQ + bx*64 + nt*32 + ln) * DM + q2*8];
    f32x16 acc = {};
#pragma unroll
    for (int c = 0; c < 16; ++c) {
        bf16x8 af = cvt8(arow + c*16);
        bf16x8 bf_ = cvt8(brow + c*16);
        acc = __builtin_amdgcn_mfma_f32_32x32x16_bf16(af, bf_, acc, 0, 0, 0);
    }
    // tile index: (b*128 + s32)*4 + (2*mt + kc)
    size_t base = (((size_t)(b*128 + bx*2 + nt)) * 4 + 2*mt) * 64;
    repack_store(acc, q2, l, OUT, base);
}

// ---------------------------------------------------------------------------
// V projection: D[s][e] = sum_d X[s][d] * Wv[e][d]. A = X rows (m=s=kv-pos),
// B = Wv rows (n=e). Frag-packed for PV B-operand: chunk (e-tile32, kv-chunk16).
// grid (S/32, B), 256 thr; waves split e-tiles (2 each).
// ---------------------------------------------------------------------------
__global__ __launch_bounds__(256) void proj_v(const float* __restrict__ Xv, const float* __restrict__ Wv,
                                              uint4* __restrict__ vf) {
    const int bx = blockIdx.x, b = blockIdx.y;
    const int tid = threadIdx.x, w = tid >> 6, l = tid & 63, ln = l & 31, q2 = l >> 5;
    const float* arow = &Xv[((size_t)b*SEQ + bx*32 + ln) * DM + q2*8];
    bf16x8 af[16];
#pragma unroll
    for (int c = 0; c < 16; ++c) af[c] = cvt8(arow + c*16);
#pragma unroll
    for (int ntl = 0; ntl < 2; ++ntl) {
        const int nt = 2*w + ntl;                      // e-tile 0..7
        const float* brow = &Wv[(size_t)(nt*32 + ln) * DM + q2*8];
        f32x16 acc = {};
#pragma unroll
        for (int c = 0; c < 16; ++c) {
            bf16x8 bf_ = cvt8(brow + c*16);
            acc = __builtin_amdgcn_mfma_f32_32x32x16_bf16(af[c], bf_, acc, 0, 0, 0);
        }
        // chunk index: (b*8 + e-tile)*256 + (s32*2 + kc)
        size_t base = (((size_t)(b*8 + nt)) * 256 + (size_t)bx*2) * 64;
        repack_store(acc, q2, l, vf, base);
    }
}

// ---------------------------------------------------------------------------
// Flash attention, causal, no-max softmax. Block = 32 Q-rows; K-tile 128.
// S^T = K·Q^T via MFMA (A=K frag, B=Q frag) so P is k-contiguous per lane.
// V/K/Q fragments loaded coalesced from frag-packed buffers. LDS: P only.
// ---------------------------------------------------------------------------
__global__ __launch_bounds__(256, 2) void attn(const uint4* __restrict__ qf,
                                               const uint4* __restrict__ kf,
                                               const uint4* __restrict__ vf,
                                               float* __restrict__ out) {
    __shared__ unsigned short Pr[2][32][140];   // [buf][q-row][kv-local], stride 140 -> 8B align, 2-way banks
    __shared__ float denp[4][2][32];
    __shared__ float invd[32];

    const int bid = blockIdx.x;
    const int u = bid >> 2, b = bid & 3;
    const int th = (u < 64) ? (127 - u) : (u - 64);    // fold: long blocks first, balanced pairs
    const int r0 = th * 32;
    const int tid = threadIdx.x, w = tid >> 6, l = tid & 63, ln = l & 31, q2 = l >> 5;
    const int niter = th / 4 + 1;
    const float cfac = 0.18033688011112042f;           // log2(e)/sqrt(64)

    bf16x8 qv[4];                                      // Q B-frags, d-chunks 0..3
#pragma unroll
    for (int c = 0; c < 4; ++c)
        qv[c] = u4bf(qf[((size_t)(b*128 + th) * 4 + c) * 64 + l]);

    f32x16 oa0 = {}, oa1 = {};                         // O acc: e-tiles 2w, 2w+1
    float den = 0.f;

    for (int jt = 0; jt < niter; ++jt) {
        // ---- S^T subtile: K rows (this wave's 32) x 32 Q-cols ----
        f32x16 s = {};
#pragma unroll
        for (int c = 0; c < 4; ++c) {
            bf16x8 ka = u4bf(kf[((size_t)(b*128 + jt*4 + w) * 4 + c) * 64 + l]);
            s = __builtin_amdgcn_mfma_f32_32x32x16_bf16(ka, qv[c], s, 0, 0, 0);
        }
        const bool last = (jt == niter - 1);
        const int kbase = jt*128 + w*32 + 4*q2;
        const int rho = r0 + ln;
        float p[16];
#pragma unroll
        for (int r = 0; r < 16; ++r) {
            int kpos = kbase + (r & 3) + 8*(r >> 2);
            float e = __builtin_exp2f(s[r] * cfac);
            p[r] = (last && (kpos > rho)) ? 0.f : e;   // causal mask (only last iter can cross diag)
            den += p[r];
        }
        // ---- P -> LDS (row = q-local = ln, col = kv-local, b64 packed) ----
#pragma unroll
        for (int h = 0; h < 4; ++h) {
            unsigned int lo = pk2bf(p[4*h + 0], p[4*h + 1]);
            unsigned int hi = pk2bf(p[4*h + 2], p[4*h + 3]);
            *(uint2*)&Pr[jt & 1][ln][w*32 + 8*h + 4*q2] = make_uint2(lo, hi);
        }
        __syncthreads();
        // ---- O += P·V : A = P frag (rows = q), B = V frag (cols = e) ----
#pragma unroll
        for (int c = 0; c < 8; ++c) {
            uint2 a0 = *(const uint2*)&Pr[jt & 1][ln][c*16 + q2*8];
            uint2 a1 = *(const uint2*)&Pr[jt & 1][ln][c*16 + q2*8 + 4];
            bf16x8 pa = u4bf(make_uint4(a0.x, a0.y, a1.x, a1.y));
            bf16x8 vb0 = u4bf(vf[((size_t)(b*8 + 2*w + 0) * 256 + jt*8 + c) * 64 + l]);
            oa0 = __builtin_amdgcn_mfma_f32_32x32x16_bf16(pa, vb0, oa0, 0, 0, 0);
            bf16x8 vb1 = u4bf(vf[((size_t)(b*8 + 2*w + 1) * 256 + jt*8 + c) * 64 + l]);
            oa1 = __builtin_amdgcn_mfma_f32_32x32x16_bf16(pa, vb1, oa1, 0, 0, 0);
        }
    }

    // ---- den reduce (per q-row = ln, across 4 waves x 2 halves) ----
    __syncthreads();
    denp[w][q2][ln] = den;
    __syncthreads();
    if (tid < 32) {
        float ssum = 0.f;
#pragma unroll
        for (int ww = 0; ww < 4; ++ww)
#pragma unroll
            for (int qq = 0; qq < 2; ++qq) ssum += denp[ww][qq][tid];
        invd[tid] = 1.0f / ssum;
    }
    __syncthreads();

    // ---- epilogue: normalize + store fp32 ----
#pragma unroll
    for (int r = 0; r < 16; ++r) {
        int rrow = (r & 3) + 8*(r >> 2) + 4*q2;
        float iv = invd[rrow];
        size_t row_ofs = ((size_t)b*SEQ + r0 + rrow) * DM;
        out[row_ofs + (2*w + 0)*32 + ln] = oa0[r] * iv;
        out[row_ofs + (2*w + 1)*32 + ln] = oa1[r] * iv;
    }
}

// ---------------------------------------------------------------------------
extern "C" void kernel_launch(void* const* d_in, const int* in_sizes, int n_in,
                              void* d_out, int out_size, void* d_ws, size_t ws_size,
                              hipStream_t stream) {
    const float* enc_q = (const float*)d_in[0];
    const float* enc_k = (const float*)d_in[1];
    const float* enc_v = (const float*)d_in[2];
    // d_in[3] = mask (deterministic causal triu) — not needed
    const float* Wq = (const float*)d_in[4];
    const float* Wk = (const float*)d_in[5];
    const float* Wv = (const float*)d_in[6];
    float* out = (float*)d_out;

    uint4* qf = (uint4*)d_ws;          // [B][128 s-tiles][4 kc][64 lanes] = 2MB
    uint4* kf = qf + 131072;           // same, 2MB
    uint4* vf = kf + 131072;           // [B][8 e-tiles][256 kv-chunks][64] = 8MB

    proj_qk<<<dim3(64, 4, 2), 256, 0, stream>>>(enc_q, enc_k, Wq, Wk, qf, kf);
    proj_v<<<dim3(128, 4), 256, 0, stream>>>(enc_v, Wv, vf);
    attn<<<512, 256, 0, stream>>>(qf, kf, vf, out);
}

// Round 3
// 220.522 us; speedup vs baseline: 2.0625x; 1.2169x over previous
//
#include <hip/hip_runtime.h>

// Causal single-head attention, B=4 S=4096 Dm=256 Dqk=64, fp32 in/out.
// R3: (1) fused projection kernel: coalesced fp32 staging -> LDS -> 32x32x16
// bf16 MFMA -> frag-packed ws (same layouts as R2). (2) attention with Q-tile
// 128 (512 thr / 8 waves), K-tile 128, K-range split 1/2/3-way into 240
// uniform blocks; no-max softmax; P round-trips through LDS in A-frag-packed
// layout (conflict-free writes, canonical b128 reads), double-buffered, one
// barrier/iter. Split blocks write bf16 partial O + fp32 den; combine kernel
// finishes. (3) XCD batch-pinning: bid%8 -> batch so each XCD's L2 holds its
// batch's 3MB of fragments.
// ws: qf 2MB + kf 2MB + vf 8MB + Op 15.7MB + Dp 0.12MB = 27.9MB.

#define BATCH 4
#define SEQ   4096
#define DM    256
#define DQK   64

typedef __bf16 bf16x8 __attribute__((ext_vector_type(8)));
typedef float  f32x16 __attribute__((ext_vector_type(16)));

__device__ __forceinline__ unsigned int rnd16(unsigned int u) {
    return u + 0x7fffu + ((u >> 16) & 1u);          // RNE to bf16 in high half
}
__device__ __forceinline__ unsigned short f2bf(float f) {
    return (unsigned short)(rnd16(__builtin_bit_cast(unsigned int, f)) >> 16);
}
__device__ __forceinline__ unsigned int pk2bf(float lo, float hi) {
    unsigned int a = rnd16(__builtin_bit_cast(unsigned int, lo));
    unsigned int b = rnd16(__builtin_bit_cast(unsigned int, hi));
    return (a >> 16) | (b & 0xffff0000u);           // elem0 low, elem1 high
}
__device__ __forceinline__ bf16x8 u4bf(uint4 u) { return __builtin_bit_cast(bf16x8, u); }

// Repack a 32x32x16 MFMA accumulator D[m][n] (C-layout: col(n)=lane&31,
// row(m)=(r&3)+8(r>>2)+4(lane>>5)) into two 1KB fragment chunks where the
// fragment k-dim = m and lane-dim = n, then store. (Verified in R2.)
__device__ __forceinline__ void repack_store(const f32x16& acc, int q2, int l,
                                             uint4* __restrict__ out, size_t tile_ofs_u4) {
    unsigned int d0[4], d1[4], p0[4], p1[4];
#pragma unroll
    for (int h = 0; h < 4; ++h) {
        d0[h] = pk2bf(acc[4*h + 0], acc[4*h + 1]);
        d1[h] = pk2bf(acc[4*h + 2], acc[4*h + 3]);
        p0[h] = __shfl_xor((int)d0[h], 32);
        p1[h] = __shfl_xor((int)d1[h], 32);
    }
#pragma unroll
    for (int kc = 0; kc < 2; ++kc) {
        int h = 2*kc + q2;
        uint4 v = (q2 == 0) ? make_uint4(d0[h], d1[h], p0[h], p1[h])
                            : make_uint4(p0[h], p1[h], d0[h], d1[h]);
        out[tile_ofs_u4 + (size_t)kc * 64 + l] = v;
    }
}

// ---------------------------------------------------------------------------
// Fused projection kernel. grid (64 s-tiles of 64, 4 batch, 3 proj{Q,K,V}).
// Coalesced fp32 float4 staging -> bf16 row-major LDS (+8 short pad) ->
// 32x32x16 MFMA -> repack_store into frag-packed ws.
//   qf/kf: [b][s-tile32][d-chunk16 (4)][lane64] uint4    (frag k-dim = d_qk)
//   vf:    [b][e-tile32 (8)][kv-chunk16 (256)][lane64]   (frag k-dim = kv-pos)
// ---------------------------------------------------------------------------
__global__ __launch_bounds__(256) void proj(const float* __restrict__ Xq,
                                            const float* __restrict__ Xk,
                                            const float* __restrict__ Xv,
                                            const float* __restrict__ Wq,
                                            const float* __restrict__ Wk,
                                            const float* __restrict__ Wv,
                                            uint4* __restrict__ qf,
                                            uint4* __restrict__ kf,
                                            uint4* __restrict__ vf) {
    __shared__ unsigned short Xs[64][264];   // 64 rows x 256 (+8 pad)
    __shared__ unsigned short Ws[64][264];

    const int z = blockIdx.z;                // 0=Q 1=K 2=V
    const int bx = blockIdx.x, b = blockIdx.y;
    const float* X = (z == 0) ? Xq : (z == 1) ? Xk : Xv;
    const float* W = (z == 0) ? Wq : (z == 1) ? Wk : Wv;
    const int s0 = bx * 64;
    const int tid = threadIdx.x, w = tid >> 6, l = tid & 63, ln = l & 31, q2 = l >> 5;

    // stage X tile: coalesced float4 reads, bf16 LDS rows
#pragma unroll
    for (int i = 0; i < 16; ++i) {
        int f = i * 256 + tid;
        int r = f >> 6, c4 = f & 63;
        float4 xv = *(const float4*)&X[((size_t)b * SEQ + s0 + r) * DM + c4 * 4];
        ushort4 h; h.x = f2bf(xv.x); h.y = f2bf(xv.y); h.z = f2bf(xv.z); h.w = f2bf(xv.w);
        *(ushort4*)&Xs[r][c4 * 4] = h;
    }

    if (z < 2) {
        // ---- Q/K: output D[m=e (64)][n=s (64)] ----
#pragma unroll
        for (int i = 0; i < 16; ++i) {
            int f = i * 256 + tid;
            int r = f >> 6, c4 = f & 63;
            float4 wv = *(const float4*)&W[(size_t)r * DM + c4 * 4];
            ushort4 h; h.x = f2bf(wv.x); h.y = f2bf(wv.y); h.z = f2bf(wv.z); h.w = f2bf(wv.w);
            *(ushort4*)&Ws[r][c4 * 4] = h;
        }
        __syncthreads();
        const int msub = w >> 1, nsub = w & 1;          // e-sub, s-sub
        f32x16 a0 = {}, a1 = {};
#pragma unroll
        for (int c = 0; c < 16; c += 2) {
            bf16x8 af0 = u4bf(*(const uint4*)&Ws[msub*32 + ln][c*16 + q2*8]);
            bf16x8 bf0 = u4bf(*(const uint4*)&Xs[nsub*32 + ln][c*16 + q2*8]);
            a0 = __builtin_amdgcn_mfma_f32_32x32x16_bf16(af0, bf0, a0, 0, 0, 0);
            bf16x8 af1 = u4bf(*(const uint4*)&Ws[msub*32 + ln][(c+1)*16 + q2*8]);
            bf16x8 bf1 = u4bf(*(const uint4*)&Xs[nsub*32 + ln][(c+1)*16 + q2*8]);
            a1 = __builtin_amdgcn_mfma_f32_32x32x16_bf16(af1, bf1, a1, 0, 0, 0);
        }
        f32x16 acc = a0 + a1;
        size_t base = (((size_t)(b*128 + bx*2 + nsub)) * 4 + 2*msub) * 64;
        repack_store(acc, q2, l, (z == 0) ? qf : kf, base);
    } else {
        // ---- V: output D[m=s (64)][n=e (256, 4 chunks of 64)] ----
        const int msub = w & 1, nsub = w >> 1;          // s-sub, e-sub(within chunk)
        for (int ec = 0; ec < 4; ++ec) {
            __syncthreads();                            // protect Ws reuse (covers Xs too)
#pragma unroll
            for (int i = 0; i < 16; ++i) {
                int f = i * 256 + tid;
                int r = f >> 6, c4 = f & 63;
                float4 wv = *(const float4*)&W[(size_t)(ec*64 + r) * DM + c4 * 4];
                ushort4 h; h.x = f2bf(wv.x); h.y = f2bf(wv.y); h.z = f2bf(wv.z); h.w = f2bf(wv.w);
                *(ushort4*)&Ws[r][c4 * 4] = h;
            }
            __syncthreads();
            f32x16 a0 = {}, a1 = {};
#pragma unroll
            for (int c = 0; c < 16; c += 2) {
                bf16x8 af0 = u4bf(*(const uint4*)&Xs[msub*32 + ln][c*16 + q2*8]);
                bf16x8 bf0 = u4bf(*(const uint4*)&Ws[nsub*32 + ln][c*16 + q2*8]);
                a0 = __builtin_amdgcn_mfma_f32_32x32x16_bf16(af0, bf0, a0, 0, 0, 0);
                bf16x8 af1 = u4bf(*(const uint4*)&Xs[msub*32 + ln][(c+1)*16 + q2*8]);
                bf16x8 bf1 = u4bf(*(const uint4*)&Ws[nsub*32 + ln][(c+1)*16 + q2*8]);
                a1 = __builtin_amdgcn_mfma_f32_32x32x16_bf16(af1, bf1, a1, 0, 0, 0);
            }
            f32x16 acc = a0 + a1;
            int et = ec*2 + nsub;
            size_t base = (((size_t)(b*8 + et)) * 256 + (size_t)bx*4 + msub*2) * 64;
            repack_store(acc, q2, l, vf, base);
        }
    }
}

// ---------------------------------------------------------------------------
// Attention. 240 blocks x 512 thr. Block = (batch, Q-supertile T of 128 rows,
// K-chunk cc of nc(T)). Wave w: S^T tile (k-sub w&3, q-pair w>>2), PV e-tile w.
// ---------------------------------------------------------------------------
__global__ __launch_bounds__(512) void attn(const uint4* __restrict__ qf,
                                            const uint4* __restrict__ kf,
                                            const uint4* __restrict__ vf,
                                            float* __restrict__ out,
                                            unsigned short* __restrict__ Op,
                                            float* __restrict__ Dp) {
    __shared__ uint4 Pb[2][4][8][64];        // [buf][q-sub][k-chunk16][lane] 64KB
    __shared__ float denp[8][2][64];
    __shared__ float dfin[128];

    // XCD batch-pinning: slot = bid&7 -> batch = slot>>1 (XCD = bid%8 heuristic)
    const int bid = blockIdx.x;
    const int slot = bid & 7, u = bid >> 3;
    const int b = slot >> 1;
    const int task = u * 2 + (slot & 1);     // [0,60)
    int T, cc, nc;
    if (task < 12)      { T = task;                cc = 0;             nc = 1; }
    else if (task < 36) { int q = task - 12; T = 12 + (q >> 1); cc = q & 1;     nc = 2; }
    else                { int q = task - 36; T = 24 + q / 3;    cc = q - 3*(q/3); nc = 3; }
    const int n = T + 1;                     // k-tiles of 128
    const int j0 = cc * n / nc, j1 = (cc + 1) * n / nc;

    const int tid = threadIdx.x, w = tid >> 6, l = tid & 63, ln = l & 31, q2 = l >> 5;
    const int ks = w & 3, qp = w >> 2;       // k-sub, q-pair
    const float cfac = 0.18033688011112042f; // log2(e)/sqrt(64)

    // Q B-frags for this wave's two q-subs (held all kernel)
    bf16x8 qv[2][4];
#pragma unroll
    for (int g = 0; g < 2; ++g)
#pragma unroll
        for (int c = 0; c < 4; ++c)
            qv[g][c] = u4bf(qf[(((size_t)b*128 + T*4 + qp*2 + g) * 4 + c) * 64 + l]);

    f32x16 oa[4] = {};                       // O[q-sub][e-tile w], fp32
    float den[2] = {0.f, 0.f};

    uint4 kaf[4];
#pragma unroll
    for (int c = 0; c < 4; ++c)
        kaf[c] = kf[(((size_t)b*128 + j0*4 + ks) * 4 + c) * 64 + l];

    for (int jt = j0; jt < j1; ++jt) {
        const int buf = jt & 1;
        const bool diag = (jt == T);
        // ---- S^T: two q-groups ----
        f32x16 s0 = {}, s1 = {};
#pragma unroll
        for (int c = 0; c < 4; ++c) {
            bf16x8 ka = u4bf(kaf[c]);
            s0 = __builtin_amdgcn_mfma_f32_32x32x16_bf16(ka, qv[0][c], s0, 0, 0, 0);
            s1 = __builtin_amdgcn_mfma_f32_32x32x16_bf16(ka, qv[1][c], s1, 0, 0, 0);
        }
        // ---- exp + mask + den + pack P into LDS (A-frag-packed) ----
#pragma unroll
        for (int g = 0; g < 2; ++g) {
            const f32x16 s = g ? s1 : s0;
            const int qsub = qp*2 + g;
            float pv[16], pd = 0.f;
#pragma unroll
            for (int r = 0; r < 16; ++r) {
                float e = __builtin_exp2f(s[r] * cfac);
                if (diag) {
                    int klocal = 4*q2 + (r & 3) + 8*(r >> 2);
                    if (ks*32 + klocal > qsub*32 + ln) e = 0.f;
                }
                pv[r] = e; pd += e;
            }
            den[g] += pd;
#pragma unroll
            for (int quad = 0; quad < 4; ++quad) {
                unsigned int lo = pk2bf(pv[4*quad + 0], pv[4*quad + 1]);
                unsigned int hi = pk2bf(pv[4*quad + 2], pv[4*quad + 3]);
                int kcg = ks*2 + (quad >> 1);
                int h   = quad & 1;
                char* dst = (char*)&Pb[buf][qsub][kcg][h*32 + ln] + q2*8;
                *(uint2*)dst = make_uint2(lo, hi);
            }
        }
        __syncthreads();
        // prefetch next K-frags during PV
        if (jt + 1 < j1) {
#pragma unroll
            for (int c = 0; c < 4; ++c)
                kaf[c] = kf[(((size_t)b*128 + (jt+1)*4 + ks) * 4 + c) * 64 + l];
        }
        // ---- PV: O[q][e-tile w] += P * V ----
#pragma unroll
        for (int kc = 0; kc < 8; ++kc) {
            bf16x8 vb = u4bf(vf[(((size_t)b*8 + w) * 256 + jt*8 + kc) * 64 + l]);
#pragma unroll
            for (int qs = 0; qs < 4; ++qs) {
                bf16x8 pa = u4bf(Pb[buf][qs][kc][l]);
                oa[qs] = __builtin_amdgcn_mfma_f32_32x32x16_bf16(pa, vb, oa[qs], 0, 0, 0);
            }
        }
    }

    // ---- den reduction across waves/halves ----
    denp[w][0][l] = den[0];
    denp[w][1][l] = den[1];
    __syncthreads();
    if (tid < 128) {
        int qsub = tid >> 5, qln = tid & 31;
        int g = qsub & 1, wp = qsub >> 1;
        float sden = 0.f;
#pragma unroll
        for (int k4 = 0; k4 < 4; ++k4)
#pragma unroll
            for (int hh = 0; hh < 2; ++hh)
                sden += denp[wp*4 + k4][g][hh*32 + qln];
        dfin[tid] = (nc == 1) ? 1.0f / sden : sden;
    }
    __syncthreads();

    if (nc == 1) {
        // sole owner: normalize + store fp32 directly
#pragma unroll
        for (int qs = 0; qs < 4; ++qs)
#pragma unroll
            for (int r = 0; r < 16; ++r) {
                int qrow = qs*32 + (r & 3) + 8*(r >> 2) + 4*q2;
                out[((size_t)b*SEQ + T*128 + qrow) * DM + w*32 + ln] = oa[qs][r] * dfin[qrow];
            }
    } else {
        size_t pidx = (size_t)(b*20 + (T - 12)) * 3 + cc;
#pragma unroll
        for (int qs = 0; qs < 4; ++qs)
#pragma unroll
            for (int r = 0; r < 16; ++r) {
                int qrow = qs*32 + (r & 3) + 8*(r >> 2) + 4*q2;
                Op[(pidx*128 + qrow) * DM + w*32 + ln] = f2bf(oa[qs][r]);
            }
        if (tid < 128) Dp[pidx*128 + tid] = dfin[tid];
    }
}

// ---------------------------------------------------------------------------
// Combine partials for T in [12,32). grid (20, 4, 4 q-quarters) x 256 thr.
// ---------------------------------------------------------------------------
__global__ __launch_bounds__(256) void combine(const unsigned short* __restrict__ Op,
                                               const float* __restrict__ Dp,
                                               float* __restrict__ out) {
    const int T = 12 + blockIdx.x, b = blockIdx.y, qq = blockIdx.z;
    const int nc = (T < 24) ? 2 : 3;
    const int t = threadIdx.x;
    const size_t base_p = (size_t)(b*20 + (T - 12)) * 3;
#pragma unroll 4
    for (int r = 0; r < 32; ++r) {
        int q = qq*32 + r;
        float sum = 0.f, den = 0.f;
        for (int c = 0; c < nc; ++c) {
            size_t pidx = base_p + c;
            unsigned int uv = Op[(pidx*128 + q) * DM + t];
            sum += __builtin_bit_cast(float, uv << 16);
            den += Dp[pidx*128 + q];
        }
        out[((size_t)b*SEQ + T*128 + q) * DM + t] = sum / den;
    }
}

// ---------------------------------------------------------------------------
extern "C" void kernel_launch(void* const* d_in, const int* in_sizes, int n_in,
                              void* d_out, int out_size, void* d_ws, size_t ws_size,
                              hipStream_t stream) {
    const float* enc_q = (const float*)d_in[0];
    const float* enc_k = (const float*)d_in[1];
    const float* enc_v = (const float*)d_in[2];
    // d_in[3] = mask (deterministic causal triu) — not needed
    const float* Wq = (const float*)d_in[4];
    const float* Wk = (const float*)d_in[5];
    const float* Wv = (const float*)d_in[6];
    float* out = (float*)d_out;

    uint4* qf = (uint4*)d_ws;                      // 2MB
    uint4* kf = qf + 131072;                       // 2MB
    uint4* vf = kf + 131072;                       // 8MB
    unsigned short* Op = (unsigned short*)(vf + 524288);   // [4][20][3][128][256] bf16, 15.73MB
    float* Dp = (float*)(Op + (size_t)4*20*3*128*256);     // [4][20][3][128] f32, 122KB

    proj<<<dim3(64, 4, 3), 256, 0, stream>>>(enc_q, enc_k, enc_v, Wq, Wk, Wv, qf, kf, vf);
    attn<<<240, 512, 0, stream>>>(qf, kf, vf, out, Op, Dp);
    combine<<<dim3(20, 4, 4), 256, 0, stream>>>(Op, Dp, out);
}